// Round 2
// baseline (1302.762 us; speedup 1.0000x reference)
//
#include <hip/hip_runtime.h>
#include <stdint.h>

#define DEV __device__ __forceinline__

constexpr int B_ = 4, S_ = 2048, D_ = 1024, H_ = 16, HD_ = 64;
constexpr int BH_ = B_ * H_;   // 64
constexpr int BS_ = B_ * S_;   // 8192

typedef __attribute__((ext_vector_type(8))) short bf16x8;
typedef __attribute__((ext_vector_type(4))) float f32x4;

DEV uint16_t f2bf(float f) {
    union { float f; uint32_t u; } v; v.f = f;
    return (uint16_t)((v.u + 0x7fffu + ((v.u >> 16) & 1u)) >> 16);
}

DEV f32x4 mfma16(bf16x8 a, bf16x8 b, f32x4 c) {
    return __builtin_amdgcn_mfma_f32_16x16x32_bf16(a, b, c, 0, 0, 0);
}

// ---------------------------------------------------------------------------
// Prep: transpose weights to bf16 [n][k] layouts so B-fragments load 8
// contiguous bf16 per lane.
// WtIn[n*D+k]  = bf16(W_in[k*D+n])
// WtOut[n*D+k] = bf16(W_out[k*D+n])
// WtA[(h*HD+e)*HD+d] = bf16(W_attn[(h*HD+d)*HD+e])
// ---------------------------------------------------------------------------
__global__ __launch_bounds__(256) void k_prep(
    const float* __restrict__ Win, const float* __restrict__ Wout,
    const float* __restrict__ Wa,
    uint16_t* __restrict__ WtIn, uint16_t* __restrict__ WtOut,
    uint16_t* __restrict__ WtA) {
    int stride = gridDim.x * blockDim.x;
    int idx = blockIdx.x * blockDim.x + threadIdx.x;
    for (int i = idx; i < D_ * D_; i += stride) {
        int n = i / D_, k = i % D_;
        WtIn[i]  = f2bf(Win[(size_t)k * D_ + n]);
        WtOut[i] = f2bf(Wout[(size_t)k * D_ + n]);
    }
    for (int i = idx; i < H_ * HD_ * HD_; i += stride) {
        int h = i / (HD_ * HD_);
        int r = i % (HD_ * HD_);
        int e = r / HD_, d = r % HD_;
        WtA[i] = f2bf(Wa[((size_t)h * HD_ + d) * HD_ + e]);
    }
}

// ---------------------------------------------------------------------------
// in_proj: h = x @ W_in + b_in   (M=8192, N=1024, K=1024)
// grid (16 colblocks, 128 rowblocks), 4 waves/block, wave = 16 rows x 64 cols.
// Writes hb bf16 in [BH][S][HD] layout (head-split).
// ---------------------------------------------------------------------------
__global__ __launch_bounds__(256) void k_gemm_in(
    const float* __restrict__ x, const uint16_t* __restrict__ WtIn,
    const float* __restrict__ b_in, uint16_t* __restrict__ hb) {
    const int wave = threadIdx.x >> 6, lane = threadIdx.x & 63;
    const int lhi = lane >> 4, llo = lane & 15;
    const int col0 = blockIdx.x * 64;
    const int row0 = blockIdx.y * 64 + wave * 16;

    f32x4 acc[4] = {};
    const float* xrow = x + (size_t)(row0 + llo) * D_;
    for (int kc = 0; kc < D_ / 32; ++kc) {
        const int k0 = kc * 32 + lhi * 8;
        float4 xa = *reinterpret_cast<const float4*>(xrow + k0);
        float4 xc = *reinterpret_cast<const float4*>(xrow + k0 + 4);
        bf16x8 a;
        a[0] = (short)f2bf(xa.x); a[1] = (short)f2bf(xa.y);
        a[2] = (short)f2bf(xa.z); a[3] = (short)f2bf(xa.w);
        a[4] = (short)f2bf(xc.x); a[5] = (short)f2bf(xc.y);
        a[6] = (short)f2bf(xc.z); a[7] = (short)f2bf(xc.w);
#pragma unroll
        for (int nt = 0; nt < 4; ++nt) {
            const uint16_t* bp = WtIn + (size_t)(col0 + nt * 16 + llo) * D_ + k0;
            bf16x8 b = *reinterpret_cast<const bf16x8*>(bp);
            acc[nt] = mfma16(a, b, acc[nt]);
        }
    }
#pragma unroll
    for (int nt = 0; nt < 4; ++nt) {
        const int c = col0 + nt * 16 + llo;
        const float bias = b_in[c];
        const int bhcol = c >> 6, d = c & 63;
#pragma unroll
        for (int r = 0; r < 4; ++r) {
            const int m = row0 + lhi * 4 + r;
            const int b_ = m >> 11, s = m & 2047;
            hb[((size_t)(b_ * H_ + bhcol) * S_ + s) * HD_ + d] = f2bf(acc[nt][r] + bias);
        }
    }
}

// ---------------------------------------------------------------------------
// Transpose hb [bh][s][d] -> hbT [bh][d][s]  (for PV B-operand)
// ---------------------------------------------------------------------------
__global__ __launch_bounds__(256) void k_transpose(
    const uint16_t* __restrict__ hb, uint16_t* __restrict__ hbT) {
    __shared__ uint16_t tile[64][72];   // pad to 144B rows (16B aligned)
    const int st = blockIdx.x, bh = blockIdx.y;
    const int s0 = st * 64;
    const int t = threadIdx.x;
    {
        const int r = t >> 2, c0 = (t & 3) * 16;
        const uint16_t* src = hb + ((size_t)bh * S_ + s0 + r) * HD_ + c0;
        *reinterpret_cast<bf16x8*>(&tile[r][c0])     = *reinterpret_cast<const bf16x8*>(src);
        *reinterpret_cast<bf16x8*>(&tile[r][c0 + 8]) = *reinterpret_cast<const bf16x8*>(src + 8);
    }
    __syncthreads();
    {
        const int d = t >> 2, c0 = (t & 3) * 16;
        uint16_t tmp[16];
#pragma unroll
        for (int j = 0; j < 16; ++j) tmp[j] = tile[c0 + j][d];
        uint16_t* dst = hbT + ((size_t)bh * HD_ + d) * S_ + s0 + c0;
        *reinterpret_cast<bf16x8*>(dst)     = *reinterpret_cast<const bf16x8*>(tmp);
        *reinterpret_cast<bf16x8*>(dst + 8) = *reinterpret_cast<const bf16x8*>(tmp + 8);
    }
}

// ---------------------------------------------------------------------------
// q-proj: q[bh][s][e] = sum_d h[bh][s][d] * W_attn[h][d][e]
// grid (32 rowtiles, 64 bh), wave = 16 rows x 64 cols, K=64 (2 MFMA chunks)
// ---------------------------------------------------------------------------
__global__ __launch_bounds__(256) void k_gemm_q(
    const uint16_t* __restrict__ hb, const uint16_t* __restrict__ WtA,
    uint16_t* __restrict__ qb) {
    const int wave = threadIdx.x >> 6, lane = threadIdx.x & 63;
    const int lhi = lane >> 4, llo = lane & 15;
    const int bh = blockIdx.y;
    const int h = bh & (H_ - 1);
    const int row0 = blockIdx.x * 64 + wave * 16;

    const uint16_t* hrow = hb + ((size_t)bh * S_ + row0 + llo) * HD_;
    f32x4 acc[4] = {};
#pragma unroll
    for (int kc = 0; kc < 2; ++kc) {
        const int k0 = kc * 32 + lhi * 8;
        bf16x8 a = *reinterpret_cast<const bf16x8*>(hrow + k0);
#pragma unroll
        for (int nt = 0; nt < 4; ++nt) {
            bf16x8 b = *reinterpret_cast<const bf16x8*>(
                WtA + ((size_t)h * HD_ + nt * 16 + llo) * HD_ + k0);
            acc[nt] = mfma16(a, b, acc[nt]);
        }
    }
#pragma unroll
    for (int nt = 0; nt < 4; ++nt) {
        const int e = nt * 16 + llo;
#pragma unroll
        for (int r = 0; r < 4; ++r) {
            const int s = row0 + lhi * 4 + r;
            qb[((size_t)bh * S_ + s) * HD_ + e] = f2bf(acc[nt][r]);
        }
    }
}

// ---------------------------------------------------------------------------
// attention weights: scores = q.h^T / 64, softmax rows, write w fp32.
// Two passes over K (2048): pass1 sum of exp per row, pass2 write w.
// wave = 16 Q rows x full 2048 cols in chunks of 16.
// Scores are tiny (|s| < ~0.2) so exp(s) without max-subtraction is exact
// softmax mathematically (matches reference).
// ---------------------------------------------------------------------------
__global__ __launch_bounds__(256) void k_attn_w(
    const uint16_t* __restrict__ qb, const uint16_t* __restrict__ hb,
    float* __restrict__ w_out) {
    const int wave = threadIdx.x >> 6, lane = threadIdx.x & 63;
    const int lhi = lane >> 4, llo = lane & 15;
    const int bh = blockIdx.y;
    const int row0 = blockIdx.x * 64 + wave * 16;
    constexpr float inv_hd = 1.0f / 64.0f;

    const uint16_t* qrow = qb + ((size_t)bh * S_ + row0 + llo) * HD_;
    const bf16x8 a0 = *reinterpret_cast<const bf16x8*>(qrow + lhi * 8);
    const bf16x8 a1 = *reinterpret_cast<const bf16x8*>(qrow + 32 + lhi * 8);
    const uint16_t* hbase = hb + (size_t)bh * S_ * HD_;

    float sume[4] = {0.f, 0.f, 0.f, 0.f};
    for (int tc = 0; tc < S_ / 16; ++tc) {
        const uint16_t* hrow = hbase + (size_t)(tc * 16 + llo) * HD_ + lhi * 8;
        bf16x8 b0 = *reinterpret_cast<const bf16x8*>(hrow);
        bf16x8 b1 = *reinterpret_cast<const bf16x8*>(hrow + 32);
        f32x4 acc = {};
        acc = mfma16(a0, b0, acc);
        acc = mfma16(a1, b1, acc);
#pragma unroll
        for (int r = 0; r < 4; ++r) sume[r] += __expf(acc[r] * inv_hd);
    }
#pragma unroll
    for (int r = 0; r < 4; ++r) {
        float v = sume[r];
        v += __shfl_xor(v, 1); v += __shfl_xor(v, 2);
        v += __shfl_xor(v, 4); v += __shfl_xor(v, 8);
        sume[r] = 1.0f / v;     // all 16 lanes of the group hold the row sum
    }
    for (int tc = 0; tc < S_ / 16; ++tc) {
        const uint16_t* hrow = hbase + (size_t)(tc * 16 + llo) * HD_ + lhi * 8;
        bf16x8 b0 = *reinterpret_cast<const bf16x8*>(hrow);
        bf16x8 b1 = *reinterpret_cast<const bf16x8*>(hrow + 32);
        f32x4 acc = {};
        acc = mfma16(a0, b0, acc);
        acc = mfma16(a1, b1, acc);
        const int col = tc * 16 + llo;
#pragma unroll
        for (int r = 0; r < 4; ++r) {
            const size_t row = (size_t)bh * S_ + row0 + lhi * 4 + r;
            w_out[row * S_ + col] = __expf(acc[r] * inv_hd) * sume[r];
        }
    }
}

// ---------------------------------------------------------------------------
// PV: pv[bh][s][d] = sum_t w[bh][s][t] * h[bh][t][d]   (M=2048,N=64,K=2048)
// A = w (fp32 -> bf16 on the fly), B from hbT (contiguous t per lane).
// Writes pvb bf16 in [B][S][D] layout for out_proj.
// ---------------------------------------------------------------------------
__global__ __launch_bounds__(256) void k_gemm_pv(
    const float* __restrict__ w, const uint16_t* __restrict__ hbT,
    uint16_t* __restrict__ pvb) {
    const int wave = threadIdx.x >> 6, lane = threadIdx.x & 63;
    const int lhi = lane >> 4, llo = lane & 15;
    const int bh = blockIdx.y;
    const int b_ = bh >> 4, h = bh & (H_ - 1);
    const int row0 = blockIdx.x * 64 + wave * 16;

    const float* wrow = w + ((size_t)bh * S_ + row0 + llo) * S_;
    const uint16_t* hTb = hbT + (size_t)bh * HD_ * S_;
    f32x4 acc[4] = {};
    for (int kc = 0; kc < S_ / 32; ++kc) {
        const int k0 = kc * 32 + lhi * 8;
        float4 wa = *reinterpret_cast<const float4*>(wrow + k0);
        float4 wb = *reinterpret_cast<const float4*>(wrow + k0 + 4);
        bf16x8 a;
        a[0] = (short)f2bf(wa.x); a[1] = (short)f2bf(wa.y);
        a[2] = (short)f2bf(wa.z); a[3] = (short)f2bf(wa.w);
        a[4] = (short)f2bf(wb.x); a[5] = (short)f2bf(wb.y);
        a[6] = (short)f2bf(wb.z); a[7] = (short)f2bf(wb.w);
#pragma unroll
        for (int nt = 0; nt < 4; ++nt) {
            bf16x8 b = *reinterpret_cast<const bf16x8*>(
                hTb + (size_t)(nt * 16 + llo) * S_ + k0);
            acc[nt] = mfma16(a, b, acc[nt]);
        }
    }
#pragma unroll
    for (int nt = 0; nt < 4; ++nt) {
        const int d = nt * 16 + llo;
#pragma unroll
        for (int r = 0; r < 4; ++r) {
            const int s = row0 + lhi * 4 + r;
            pvb[((size_t)(b_ * S_ + s)) * D_ + h * HD_ + d] = f2bf(acc[nt][r]);
        }
    }
}

// ---------------------------------------------------------------------------
// out_proj: out = pv @ W_out + b_out   (M=8192, N=1024, K=1024), fp32 out
// ---------------------------------------------------------------------------
__global__ __launch_bounds__(256) void k_gemm_out(
    const uint16_t* __restrict__ pvb, const uint16_t* __restrict__ WtOut,
    const float* __restrict__ b_out, float* __restrict__ out) {
    const int wave = threadIdx.x >> 6, lane = threadIdx.x & 63;
    const int lhi = lane >> 4, llo = lane & 15;
    const int col0 = blockIdx.x * 64;
    const int row0 = blockIdx.y * 64 + wave * 16;

    const uint16_t* prow = pvb + (size_t)(row0 + llo) * D_;
    f32x4 acc[4] = {};
    for (int kc = 0; kc < D_ / 32; ++kc) {
        const int k0 = kc * 32 + lhi * 8;
        bf16x8 a = *reinterpret_cast<const bf16x8*>(prow + k0);
#pragma unroll
        for (int nt = 0; nt < 4; ++nt) {
            bf16x8 b = *reinterpret_cast<const bf16x8*>(
                WtOut + (size_t)(col0 + nt * 16 + llo) * D_ + k0);
            acc[nt] = mfma16(a, b, acc[nt]);
        }
    }
#pragma unroll
    for (int nt = 0; nt < 4; ++nt) {
        const int c = col0 + nt * 16 + llo;
        const float bias = b_out[c];
#pragma unroll
        for (int r = 0; r < 4; ++r) {
            out[(size_t)(row0 + lhi * 4 + r) * D_ + c] = acc[nt][r] + bias;
        }
    }
}

// ---------------------------------------------------------------------------
extern "C" void kernel_launch(void* const* d_in, const int* in_sizes, int n_in,
                              void* d_out, int out_size, void* d_ws, size_t ws_size,
                              hipStream_t stream) {
    const float* x      = (const float*)d_in[0];
    const float* W_attn = (const float*)d_in[1];
    const float* W_in   = (const float*)d_in[2];
    const float* b_in   = (const float*)d_in[3];
    const float* W_out  = (const float*)d_in[4];
    const float* b_out  = (const float*)d_in[5];

    float* out   = (float*)d_out;                       // [B,S,D]
    float* w_out = out + (size_t)BS_ * D_;              // [B,H,S,S]

    uint8_t* ws = (uint8_t*)d_ws;
    auto carve = [&](size_t elems) {
        uint16_t* p = (uint16_t*)ws;
        ws += ((elems * sizeof(uint16_t) + 255) / 256) * 256;
        return p;
    };
    uint16_t* WtIn  = carve((size_t)D_ * D_);
    uint16_t* WtOut = carve((size_t)D_ * D_);
    uint16_t* WtA   = carve((size_t)H_ * HD_ * HD_);
    uint16_t* hb    = carve((size_t)BH_ * S_ * HD_);
    uint16_t* hbT   = carve((size_t)BH_ * HD_ * S_);
    uint16_t* qb    = carve((size_t)BH_ * S_ * HD_);
    uint16_t* pvb   = carve((size_t)BS_ * D_);

    hipLaunchKernelGGL(k_prep, dim3(1024), dim3(256), 0, stream,
                       W_in, W_out, W_attn, WtIn, WtOut, WtA);
    hipLaunchKernelGGL(k_gemm_in, dim3(16, 128), dim3(256), 0, stream,
                       x, WtIn, b_in, hb);
    hipLaunchKernelGGL(k_transpose, dim3(32, 64), dim3(256), 0, stream, hb, hbT);
    hipLaunchKernelGGL(k_gemm_q, dim3(32, 64), dim3(256), 0, stream, hb, WtA, qb);
    hipLaunchKernelGGL(k_attn_w, dim3(32, 64), dim3(256), 0, stream, qb, hb, w_out);
    hipLaunchKernelGGL(k_gemm_pv, dim3(32, 64), dim3(256), 0, stream, w_out, hbT, pvb);
    hipLaunchKernelGGL(k_gemm_out, dim3(16, 128), dim3(256), 0, stream,
                       pvb, WtOut, b_out, out);
}

// Round 3
// 1300.697 us; speedup vs baseline: 1.0016x; 1.0016x over previous
//
#include <hip/hip_runtime.h>
#include <stdint.h>

#define DEV __device__ __forceinline__

constexpr int B_ = 4, S_ = 2048, D_ = 1024, H_ = 16, HD_ = 64;
constexpr int BH_ = B_ * H_;   // 64
constexpr int BS_ = B_ * S_;   // 8192

typedef __attribute__((ext_vector_type(8))) short bf16x8;
typedef __attribute__((ext_vector_type(4))) float f32x4;

DEV uint16_t f2bf(float f) {
    union { float f; uint32_t u; } v; v.f = f;
    return (uint16_t)((v.u + 0x7fffu + ((v.u >> 16) & 1u)) >> 16);
}

DEV f32x4 mfma16(bf16x8 a, bf16x8 b, f32x4 c) {
    return __builtin_amdgcn_mfma_f32_16x16x32_bf16(a, b, c, 0, 0, 0);
}

// ---------------------------------------------------------------------------
// Prep: transpose weights to bf16 [n][k] layouts so B-fragments load 8
// contiguous bf16 per lane.
// WtIn[n*D+k]  = bf16(W_in[k*D+n])
// WtOut[n*D+k] = bf16(W_out[k*D+n])
// WtA[(h*HD+e)*HD+d] = bf16(W_attn[(h*HD+d)*HD+e])
// ---------------------------------------------------------------------------
__global__ __launch_bounds__(256) void k_prep(
    const float* __restrict__ Win, const float* __restrict__ Wout,
    const float* __restrict__ Wa,
    uint16_t* __restrict__ WtIn, uint16_t* __restrict__ WtOut,
    uint16_t* __restrict__ WtA) {
    int stride = gridDim.x * blockDim.x;
    int idx = blockIdx.x * blockDim.x + threadIdx.x;
    for (int i = idx; i < D_ * D_; i += stride) {
        int n = i / D_, k = i % D_;
        WtIn[i]  = f2bf(Win[(size_t)k * D_ + n]);
        WtOut[i] = f2bf(Wout[(size_t)k * D_ + n]);
    }
    for (int i = idx; i < H_ * HD_ * HD_; i += stride) {
        int h = i / (HD_ * HD_);
        int r = i % (HD_ * HD_);
        int e = r / HD_, d = r % HD_;
        WtA[i] = f2bf(Wa[((size_t)h * HD_ + d) * HD_ + e]);
    }
}

// ---------------------------------------------------------------------------
// in_proj: h = x @ W_in + b_in   (M=8192, N=1024, K=1024)
// grid (16 colblocks, 128 rowblocks), 4 waves/block, wave = 16 rows x 64 cols.
// Writes hb bf16 in [BH][S][HD] layout (head-split).
// ---------------------------------------------------------------------------
__global__ __launch_bounds__(256) void k_gemm_in(
    const float* __restrict__ x, const uint16_t* __restrict__ WtIn,
    const float* __restrict__ b_in, uint16_t* __restrict__ hb) {
    const int wave = threadIdx.x >> 6, lane = threadIdx.x & 63;
    const int lhi = lane >> 4, llo = lane & 15;
    const int col0 = blockIdx.x * 64;
    const int row0 = blockIdx.y * 64 + wave * 16;

    f32x4 acc[4] = {};
    const float* xrow = x + (size_t)(row0 + llo) * D_;
    for (int kc = 0; kc < D_ / 32; ++kc) {
        const int k0 = kc * 32 + lhi * 8;
        float4 xa = *reinterpret_cast<const float4*>(xrow + k0);
        float4 xc = *reinterpret_cast<const float4*>(xrow + k0 + 4);
        bf16x8 a;
        a[0] = (short)f2bf(xa.x); a[1] = (short)f2bf(xa.y);
        a[2] = (short)f2bf(xa.z); a[3] = (short)f2bf(xa.w);
        a[4] = (short)f2bf(xc.x); a[5] = (short)f2bf(xc.y);
        a[6] = (short)f2bf(xc.z); a[7] = (short)f2bf(xc.w);
#pragma unroll
        for (int nt = 0; nt < 4; ++nt) {
            const uint16_t* bp = WtIn + (size_t)(col0 + nt * 16 + llo) * D_ + k0;
            bf16x8 b = *reinterpret_cast<const bf16x8*>(bp);
            acc[nt] = mfma16(a, b, acc[nt]);
        }
    }
#pragma unroll
    for (int nt = 0; nt < 4; ++nt) {
        const int c = col0 + nt * 16 + llo;
        const float bias = b_in[c];
        const int bhcol = c >> 6, d = c & 63;
#pragma unroll
        for (int r = 0; r < 4; ++r) {
            const int m = row0 + lhi * 4 + r;
            const int b_ = m >> 11, s = m & 2047;
            hb[((size_t)(b_ * H_ + bhcol) * S_ + s) * HD_ + d] = f2bf(acc[nt][r] + bias);
        }
    }
}

// ---------------------------------------------------------------------------
// Transpose hb [bh][s][d] -> hbT [bh][d][s]  (for PV B-operand)
// ---------------------------------------------------------------------------
__global__ __launch_bounds__(256) void k_transpose(
    const uint16_t* __restrict__ hb, uint16_t* __restrict__ hbT) {
    __shared__ uint16_t tile[64][72];   // pad to 144B rows (16B aligned)
    const int st = blockIdx.x, bh = blockIdx.y;
    const int s0 = st * 64;
    const int t = threadIdx.x;
    {
        const int r = t >> 2, c0 = (t & 3) * 16;
        const uint16_t* src = hb + ((size_t)bh * S_ + s0 + r) * HD_ + c0;
        *reinterpret_cast<bf16x8*>(&tile[r][c0])     = *reinterpret_cast<const bf16x8*>(src);
        *reinterpret_cast<bf16x8*>(&tile[r][c0 + 8]) = *reinterpret_cast<const bf16x8*>(src + 8);
    }
    __syncthreads();
    {
        const int d = t >> 2, c0 = (t & 3) * 16;
        uint16_t tmp[16];
#pragma unroll
        for (int j = 0; j < 16; ++j) tmp[j] = tile[c0 + j][d];
        uint16_t* dst = hbT + ((size_t)bh * HD_ + d) * S_ + s0 + c0;
        *reinterpret_cast<bf16x8*>(dst)     = *reinterpret_cast<const bf16x8*>(tmp);
        *reinterpret_cast<bf16x8*>(dst + 8) = *reinterpret_cast<const bf16x8*>(tmp + 8);
    }
}

// ---------------------------------------------------------------------------
// q-proj: q[bh][s][e] = sum_d h[bh][s][d] * W_attn[h][d][e]
// grid (32 rowtiles, 64 bh), wave = 16 rows x 64 cols, K=64 (2 MFMA chunks)
// ---------------------------------------------------------------------------
__global__ __launch_bounds__(256) void k_gemm_q(
    const uint16_t* __restrict__ hb, const uint16_t* __restrict__ WtA,
    uint16_t* __restrict__ qb) {
    const int wave = threadIdx.x >> 6, lane = threadIdx.x & 63;
    const int lhi = lane >> 4, llo = lane & 15;
    const int bh = blockIdx.y;
    const int h = bh & (H_ - 1);
    const int row0 = blockIdx.x * 64 + wave * 16;

    const uint16_t* hrow = hb + ((size_t)bh * S_ + row0 + llo) * HD_;
    f32x4 acc[4] = {};
#pragma unroll
    for (int kc = 0; kc < 2; ++kc) {
        const int k0 = kc * 32 + lhi * 8;
        bf16x8 a = *reinterpret_cast<const bf16x8*>(hrow + k0);
#pragma unroll
        for (int nt = 0; nt < 4; ++nt) {
            bf16x8 b = *reinterpret_cast<const bf16x8*>(
                WtA + ((size_t)h * HD_ + nt * 16 + llo) * HD_ + k0);
            acc[nt] = mfma16(a, b, acc[nt]);
        }
    }
#pragma unroll
    for (int nt = 0; nt < 4; ++nt) {
        const int e = nt * 16 + llo;
#pragma unroll
        for (int r = 0; r < 4; ++r) {
            const int s = row0 + lhi * 4 + r;
            qb[((size_t)bh * S_ + s) * HD_ + e] = f2bf(acc[nt][r]);
        }
    }
}

// ---------------------------------------------------------------------------
// attention weights: scores = q.h^T / 64, softmax rows, write w fp32.
// Two passes over K (2048): pass1 sum of exp per row, pass2 write w.
// wave = 16 Q rows x full 2048 cols in chunks of 16.
// Scores are tiny (|s| < ~0.2) so exp(s) without max-subtraction is exact
// softmax mathematically (matches reference).
// ---------------------------------------------------------------------------
__global__ __launch_bounds__(256) void k_attn_w(
    const uint16_t* __restrict__ qb, const uint16_t* __restrict__ hb,
    float* __restrict__ w_out) {
    const int wave = threadIdx.x >> 6, lane = threadIdx.x & 63;
    const int lhi = lane >> 4, llo = lane & 15;
    const int bh = blockIdx.y;
    const int row0 = blockIdx.x * 64 + wave * 16;
    constexpr float inv_hd = 1.0f / 64.0f;

    const uint16_t* qrow = qb + ((size_t)bh * S_ + row0 + llo) * HD_;
    const bf16x8 a0 = *reinterpret_cast<const bf16x8*>(qrow + lhi * 8);
    const bf16x8 a1 = *reinterpret_cast<const bf16x8*>(qrow + 32 + lhi * 8);
    const uint16_t* hbase = hb + (size_t)bh * S_ * HD_;

    float sume[4] = {0.f, 0.f, 0.f, 0.f};
    for (int tc = 0; tc < S_ / 16; ++tc) {
        const uint16_t* hrow = hbase + (size_t)(tc * 16 + llo) * HD_ + lhi * 8;
        bf16x8 b0 = *reinterpret_cast<const bf16x8*>(hrow);
        bf16x8 b1 = *reinterpret_cast<const bf16x8*>(hrow + 32);
        f32x4 acc = {};
        acc = mfma16(a0, b0, acc);
        acc = mfma16(a1, b1, acc);
#pragma unroll
        for (int r = 0; r < 4; ++r) sume[r] += __expf(acc[r] * inv_hd);
    }
#pragma unroll
    for (int r = 0; r < 4; ++r) {
        float v = sume[r];
        v += __shfl_xor(v, 1); v += __shfl_xor(v, 2);
        v += __shfl_xor(v, 4); v += __shfl_xor(v, 8);
        sume[r] = 1.0f / v;     // all 16 lanes of the group hold the row sum
    }
    for (int tc = 0; tc < S_ / 16; ++tc) {
        const uint16_t* hrow = hbase + (size_t)(tc * 16 + llo) * HD_ + lhi * 8;
        bf16x8 b0 = *reinterpret_cast<const bf16x8*>(hrow);
        bf16x8 b1 = *reinterpret_cast<const bf16x8*>(hrow + 32);
        f32x4 acc = {};
        acc = mfma16(a0, b0, acc);
        acc = mfma16(a1, b1, acc);
        const int col = tc * 16 + llo;
#pragma unroll
        for (int r = 0; r < 4; ++r) {
            const size_t row = (size_t)bh * S_ + row0 + lhi * 4 + r;
            w_out[row * S_ + col] = __expf(acc[r] * inv_hd) * sume[r];
        }
    }
}

// ---------------------------------------------------------------------------
// PV: pv[bh][s][d] = sum_t w[bh][s][t] * h[bh][t][d]   (M=2048,N=64,K=2048)
// A = w (fp32 -> bf16 on the fly), B from hbT (contiguous t per lane).
// Writes pvb bf16 in [B][S][D] layout for out_proj.
// ---------------------------------------------------------------------------
__global__ __launch_bounds__(256) void k_gemm_pv(
    const float* __restrict__ w, const uint16_t* __restrict__ hbT,
    uint16_t* __restrict__ pvb) {
    const int wave = threadIdx.x >> 6, lane = threadIdx.x & 63;
    const int lhi = lane >> 4, llo = lane & 15;
    const int bh = blockIdx.y;
    const int b_ = bh >> 4, h = bh & (H_ - 1);
    const int row0 = blockIdx.x * 64 + wave * 16;

    const float* wrow = w + ((size_t)bh * S_ + row0 + llo) * S_;
    const uint16_t* hTb = hbT + (size_t)bh * HD_ * S_;
    f32x4 acc[4] = {};
    for (int kc = 0; kc < S_ / 32; ++kc) {
        const int k0 = kc * 32 + lhi * 8;
        float4 wa = *reinterpret_cast<const float4*>(wrow + k0);
        float4 wb = *reinterpret_cast<const float4*>(wrow + k0 + 4);
        bf16x8 a;
        a[0] = (short)f2bf(wa.x); a[1] = (short)f2bf(wa.y);
        a[2] = (short)f2bf(wa.z); a[3] = (short)f2bf(wa.w);
        a[4] = (short)f2bf(wb.x); a[5] = (short)f2bf(wb.y);
        a[6] = (short)f2bf(wb.z); a[7] = (short)f2bf(wb.w);
#pragma unroll
        for (int nt = 0; nt < 4; ++nt) {
            bf16x8 b = *reinterpret_cast<const bf16x8*>(
                hTb + (size_t)(nt * 16 + llo) * S_ + k0);
            acc[nt] = mfma16(a, b, acc[nt]);
        }
    }
#pragma unroll
    for (int nt = 0; nt < 4; ++nt) {
        const int d = nt * 16 + llo;
#pragma unroll
        for (int r = 0; r < 4; ++r) {
            const int s = row0 + lhi * 4 + r;
            pvb[((size_t)(b_ * S_ + s)) * D_ + h * HD_ + d] = f2bf(acc[nt][r]);
        }
    }
}

// ---------------------------------------------------------------------------
// out_proj: out = pv @ W_out + b_out   (M=8192, N=1024, K=1024), fp32 out
// ---------------------------------------------------------------------------
__global__ __launch_bounds__(256) void k_gemm_out(
    const uint16_t* __restrict__ pvb, const uint16_t* __restrict__ WtOut,
    const float* __restrict__ b_out, float* __restrict__ out) {
    const int wave = threadIdx.x >> 6, lane = threadIdx.x & 63;
    const int lhi = lane >> 4, llo = lane & 15;
    const int col0 = blockIdx.x * 64;
    const int row0 = blockIdx.y * 64 + wave * 16;

    const uint16_t* prow = pvb + (size_t)(row0 + llo) * D_;
    f32x4 acc[4] = {};
    for (int kc = 0; kc < D_ / 32; ++kc) {
        const int k0 = kc * 32 + lhi * 8;
        bf16x8 a = *reinterpret_cast<const bf16x8*>(prow + k0);
#pragma unroll
        for (int nt = 0; nt < 4; ++nt) {
            bf16x8 b = *reinterpret_cast<const bf16x8*>(
                WtOut + (size_t)(col0 + nt * 16 + llo) * D_ + k0);
            acc[nt] = mfma16(a, b, acc[nt]);
        }
    }
#pragma unroll
    for (int nt = 0; nt < 4; ++nt) {
        const int c = col0 + nt * 16 + llo;
        const float bias = b_out[c];
#pragma unroll
        for (int r = 0; r < 4; ++r) {
            out[(size_t)(row0 + lhi * 4 + r) * D_ + c] = acc[nt][r] + bias;
        }
    }
}

// ---------------------------------------------------------------------------
extern "C" void kernel_launch(void* const* d_in, const int* in_sizes, int n_in,
                              void* d_out, int out_size, void* d_ws, size_t ws_size,
                              hipStream_t stream) {
    const float* x      = (const float*)d_in[0];
    const float* W_attn = (const float*)d_in[1];
    const float* W_in   = (const float*)d_in[2];
    const float* b_in   = (const float*)d_in[3];
    const float* W_out  = (const float*)d_in[4];
    const float* b_out  = (const float*)d_in[5];

    float* out   = (float*)d_out;                       // [B,S,D]
    float* w_out = out + (size_t)BS_ * D_;              // [B,H,S,S]

    uint8_t* ws = (uint8_t*)d_ws;
    auto carve = [&](size_t elems) {
        uint16_t* p = (uint16_t*)ws;
        ws += ((elems * sizeof(uint16_t) + 255) / 256) * 256;
        return p;
    };
    uint16_t* WtIn  = carve((size_t)D_ * D_);
    uint16_t* WtOut = carve((size_t)D_ * D_);
    uint16_t* WtA   = carve((size_t)H_ * HD_ * HD_);
    uint16_t* hb    = carve((size_t)BH_ * S_ * HD_);
    uint16_t* hbT   = carve((size_t)BH_ * HD_ * S_);
    uint16_t* qb    = carve((size_t)BH_ * S_ * HD_);
    uint16_t* pvb   = carve((size_t)BS_ * D_);

    hipLaunchKernelGGL(k_prep, dim3(1024), dim3(256), 0, stream,
                       W_in, W_out, W_attn, WtIn, WtOut, WtA);
    hipLaunchKernelGGL(k_gemm_in, dim3(16, 128), dim3(256), 0, stream,
                       x, WtIn, b_in, hb);
    hipLaunchKernelGGL(k_transpose, dim3(32, 64), dim3(256), 0, stream, hb, hbT);
    hipLaunchKernelGGL(k_gemm_q, dim3(32, 64), dim3(256), 0, stream, hb, WtA, qb);
    hipLaunchKernelGGL(k_attn_w, dim3(32, 64), dim3(256), 0, stream, qb, hb, w_out);
    hipLaunchKernelGGL(k_gemm_pv, dim3(32, 64), dim3(256), 0, stream, w_out, hbT, pvb);
    hipLaunchKernelGGL(k_gemm_out, dim3(16, 128), dim3(256), 0, stream,
                       pvb, WtOut, b_out, out);
}

// Round 4
// 1181.071 us; speedup vs baseline: 1.1030x; 1.1013x over previous
//
#include <hip/hip_runtime.h>
#include <hip/hip_bf16.h>
#include <stdint.h>

#define DEV __device__ __forceinline__

constexpr int B_ = 4, S_ = 2048, D_ = 1024, H_ = 16, HD_ = 64;
constexpr int BH_ = B_ * H_;   // 64
constexpr int BS_ = B_ * S_;   // 8192

typedef __attribute__((ext_vector_type(8))) short bf16x8;
typedef __attribute__((ext_vector_type(4))) float f32x4;

DEV uint16_t f2bf(float f) {
    union { float f; uint32_t u; } v; v.f = f;
    return (uint16_t)((v.u + 0x7fffu + ((v.u >> 16) & 1u)) >> 16);
}

DEV uint16_t f2bf_fast(float f) {
    __hip_bfloat16 h = __float2bfloat16(f);   // RNE, single HW cvt
    uint16_t u; __builtin_memcpy(&u, &h, 2);
    return u;
}

DEV f32x4 mfma16(bf16x8 a, bf16x8 b, f32x4 c) {
    return __builtin_amdgcn_mfma_f32_16x16x32_bf16(a, b, c, 0, 0, 0);
}

// ---------------------------------------------------------------------------
// Prep: bf16-transpose weights + bf16 convert x.
// WtIn[n*D+k]  = bf16(W_in[k*D+n]);  WtOut likewise.
// WtA[(h*HD+e)*HD+d] = bf16(W_attn[(h*HD+d)*HD+e])
// xb[i] = bf16(x[i])
// ---------------------------------------------------------------------------
__global__ __launch_bounds__(256) void k_prep(
    const float* __restrict__ Win, const float* __restrict__ Wout,
    const float* __restrict__ Wa, const float* __restrict__ x,
    uint16_t* __restrict__ WtIn, uint16_t* __restrict__ WtOut,
    uint16_t* __restrict__ WtA, uint16_t* __restrict__ xb) {
    int stride = gridDim.x * blockDim.x;
    int idx = blockIdx.x * blockDim.x + threadIdx.x;
    for (int i = idx; i < BS_ * D_ / 4; i += stride) {
        float4 v = reinterpret_cast<const float4*>(x)[i];
        ushort4 o;
        o.x = f2bf(v.x); o.y = f2bf(v.y); o.z = f2bf(v.z); o.w = f2bf(v.w);
        reinterpret_cast<ushort4*>(xb)[i] = o;
    }
    for (int i = idx; i < D_ * D_; i += stride) {
        int n = i / D_, k = i % D_;
        WtIn[i]  = f2bf(Win[(size_t)k * D_ + n]);
        WtOut[i] = f2bf(Wout[(size_t)k * D_ + n]);
    }
    for (int i = idx; i < H_ * HD_ * HD_; i += stride) {
        int h = i / (HD_ * HD_);
        int r = i % (HD_ * HD_);
        int e = r / HD_, d = r % HD_;
        WtA[i] = f2bf(Wa[((size_t)h * HD_ + d) * HD_ + e]);
    }
}

// ---------------------------------------------------------------------------
// in_proj: h = xb @ W_in + b_in   (M=8192, N=1024, K=1024), pure bf16 loads.
// Writes hb bf16 in [BH][S][HD] layout (head-split).
// ---------------------------------------------------------------------------
__global__ __launch_bounds__(256) void k_gemm_in(
    const uint16_t* __restrict__ xb, const uint16_t* __restrict__ WtIn,
    const float* __restrict__ b_in, uint16_t* __restrict__ hb) {
    const int wave = threadIdx.x >> 6, lane = threadIdx.x & 63;
    const int lhi = lane >> 4, llo = lane & 15;
    const int col0 = blockIdx.x * 64;
    const int row0 = blockIdx.y * 64 + wave * 16;

    f32x4 acc[4] = {};
    const uint16_t* xrow = xb + (size_t)(row0 + llo) * D_;
    for (int kc = 0; kc < D_ / 32; ++kc) {
        const int k0 = kc * 32 + lhi * 8;
        bf16x8 a = *reinterpret_cast<const bf16x8*>(xrow + k0);
#pragma unroll
        for (int nt = 0; nt < 4; ++nt) {
            const uint16_t* bp = WtIn + (size_t)(col0 + nt * 16 + llo) * D_ + k0;
            bf16x8 b = *reinterpret_cast<const bf16x8*>(bp);
            acc[nt] = mfma16(a, b, acc[nt]);
        }
    }
#pragma unroll
    for (int nt = 0; nt < 4; ++nt) {
        const int c = col0 + nt * 16 + llo;
        const float bias = b_in[c];
        const int bhcol = c >> 6, d = c & 63;
#pragma unroll
        for (int r = 0; r < 4; ++r) {
            const int m = row0 + lhi * 4 + r;
            const int b_ = m >> 11, s = m & 2047;
            hb[((size_t)(b_ * H_ + bhcol) * S_ + s) * HD_ + d] = f2bf(acc[nt][r] + bias);
        }
    }
}

// ---------------------------------------------------------------------------
// Transpose hb [bh][s][d] -> hbT [bh][d][s]  (for PV B-operand)
// ---------------------------------------------------------------------------
__global__ __launch_bounds__(256) void k_transpose(
    const uint16_t* __restrict__ hb, uint16_t* __restrict__ hbT) {
    __shared__ uint16_t tile[64][72];
    const int st = blockIdx.x, bh = blockIdx.y;
    const int s0 = st * 64;
    const int t = threadIdx.x;
    {
        const int r = t >> 2, c0 = (t & 3) * 16;
        const uint16_t* src = hb + ((size_t)bh * S_ + s0 + r) * HD_ + c0;
        *reinterpret_cast<bf16x8*>(&tile[r][c0])     = *reinterpret_cast<const bf16x8*>(src);
        *reinterpret_cast<bf16x8*>(&tile[r][c0 + 8]) = *reinterpret_cast<const bf16x8*>(src + 8);
    }
    __syncthreads();
    {
        const int d = t >> 2, c0 = (t & 3) * 16;
        uint16_t tmp[16];
#pragma unroll
        for (int j = 0; j < 16; ++j) tmp[j] = tile[c0 + j][d];
        uint16_t* dst = hbT + ((size_t)bh * HD_ + d) * S_ + s0 + c0;
        *reinterpret_cast<bf16x8*>(dst)     = *reinterpret_cast<const bf16x8*>(tmp);
        *reinterpret_cast<bf16x8*>(dst + 8) = *reinterpret_cast<const bf16x8*>(tmp + 8);
    }
}

// ---------------------------------------------------------------------------
// q-proj: q[bh][s][e] = sum_d h[bh][s][d] * W_attn[h][d][e]
// ---------------------------------------------------------------------------
__global__ __launch_bounds__(256) void k_gemm_q(
    const uint16_t* __restrict__ hb, const uint16_t* __restrict__ WtA,
    uint16_t* __restrict__ qb) {
    const int wave = threadIdx.x >> 6, lane = threadIdx.x & 63;
    const int lhi = lane >> 4, llo = lane & 15;
    const int bh = blockIdx.y;
    const int h = bh & (H_ - 1);
    const int row0 = blockIdx.x * 64 + wave * 16;

    const uint16_t* hrow = hb + ((size_t)bh * S_ + row0 + llo) * HD_;
    f32x4 acc[4] = {};
#pragma unroll
    for (int kc = 0; kc < 2; ++kc) {
        const int k0 = kc * 32 + lhi * 8;
        bf16x8 a = *reinterpret_cast<const bf16x8*>(hrow + k0);
#pragma unroll
        for (int nt = 0; nt < 4; ++nt) {
            bf16x8 b = *reinterpret_cast<const bf16x8*>(
                WtA + ((size_t)h * HD_ + nt * 16 + llo) * HD_ + k0);
            acc[nt] = mfma16(a, b, acc[nt]);
        }
    }
#pragma unroll
    for (int nt = 0; nt < 4; ++nt) {
        const int e = nt * 16 + llo;
#pragma unroll
        for (int r = 0; r < 4; ++r) {
            const int s = row0 + lhi * 4 + r;
            qb[((size_t)bh * S_ + s) * HD_ + e] = f2bf(acc[nt][r]);
        }
    }
}

// ---------------------------------------------------------------------------
// Fused attention: softmax(q.h^T/64) -> w_out (fp32, coalesced) AND
// pv = w @ h (bf16 MFMA via LDS A-operand), all in one kernel.
//
// Block = 64 q-rows of one bh; 4 waves, each owning 16 rows.
// Pass 1: per-row sum of exp over all 2048 t (recompute schedule).
// Pass 2: per 64-col t-chunk: scores -> normalized w tile in LDS (bf16,
//   double-buffered [2][64][72], pad-72 keeps all access patterns at <=2-way
//   bank aliasing) -> coalesced fp32 store of w + PV MFMA accumulation.
// One __syncthreads per chunk (double buffer covers the write/read hazard).
// Scores are tiny (|s|<~0.5): exp without max-subtract == exact softmax.
// ---------------------------------------------------------------------------
__global__ __launch_bounds__(256) void k_attn_fused(
    const uint16_t* __restrict__ qb, const uint16_t* __restrict__ hb,
    const uint16_t* __restrict__ hbT, float* __restrict__ w_out,
    uint16_t* __restrict__ pvb) {
    __shared__ uint16_t wb[2][64][72];
    const int wave = threadIdx.x >> 6, lane = threadIdx.x & 63;
    const int lhi = lane >> 4, llo = lane & 15;
    const int bh = blockIdx.y;
    const int row0 = blockIdx.x * 64;
    const int wrow0 = wave * 16;
    constexpr float inv_hd = 1.0f / 64.0f;

    const uint16_t* qrow = qb + ((size_t)bh * S_ + row0 + wrow0 + llo) * HD_;
    const bf16x8 a0 = *reinterpret_cast<const bf16x8*>(qrow + lhi * 8);
    const bf16x8 a1 = *reinterpret_cast<const bf16x8*>(qrow + 32 + lhi * 8);
    const uint16_t* hbase  = hb  + (size_t)bh * S_ * HD_;
    const uint16_t* hTbase = hbT + (size_t)bh * HD_ * S_;

    // ---- pass 1: row sums of exp ----
    float sume[4] = {0.f, 0.f, 0.f, 0.f};
#pragma unroll 2
    for (int tc = 0; tc < S_ / 16; ++tc) {
        const uint16_t* hrow = hbase + (size_t)(tc * 16 + llo) * HD_ + lhi * 8;
        bf16x8 b0 = *reinterpret_cast<const bf16x8*>(hrow);
        bf16x8 b1 = *reinterpret_cast<const bf16x8*>(hrow + 32);
        f32x4 acc = {};
        acc = mfma16(a0, b0, acc);
        acc = mfma16(a1, b1, acc);
#pragma unroll
        for (int r = 0; r < 4; ++r) sume[r] += __expf(acc[r] * inv_hd);
    }
    float inv[4];
#pragma unroll
    for (int r = 0; r < 4; ++r) {
        float v = sume[r];
        v += __shfl_xor(v, 1); v += __shfl_xor(v, 2);
        v += __shfl_xor(v, 4); v += __shfl_xor(v, 8);
        inv[r] = 1.0f / v;
    }

    // ---- pass 2: w tiles + PV ----
    f32x4 pv[4] = {};
    for (int tch = 0; tch < S_ / 64; ++tch) {
        const int t0 = tch * 64, buf = tch & 1;
#pragma unroll
        for (int ct = 0; ct < 4; ++ct) {
            const uint16_t* hrow =
                hbase + (size_t)(t0 + ct * 16 + llo) * HD_ + lhi * 8;
            bf16x8 b0 = *reinterpret_cast<const bf16x8*>(hrow);
            bf16x8 b1 = *reinterpret_cast<const bf16x8*>(hrow + 32);
            f32x4 acc = {};
            acc = mfma16(a0, b0, acc);
            acc = mfma16(a1, b1, acc);
#pragma unroll
            for (int r = 0; r < 4; ++r) {
                float wv = __expf(acc[r] * inv_hd) * inv[r];
                wb[buf][wrow0 + lhi * 4 + r][ct * 16 + llo] = f2bf_fast(wv);
            }
        }
        __syncthreads();
        // coalesced fp32 store of the 64x64 w tile (256B row segments)
        {
            const int t = threadIdx.x, rr = t >> 2, c0 = (t & 3) * 16;
            bf16x8 v0 = *reinterpret_cast<const bf16x8*>(&wb[buf][rr][c0]);
            bf16x8 v1 = *reinterpret_cast<const bf16x8*>(&wb[buf][rr][c0 + 8]);
            float fs[16];
#pragma unroll
            for (int j = 0; j < 8; ++j) {
                fs[j]     = __uint_as_float(((uint32_t)(uint16_t)v0[j]) << 16);
                fs[8 + j] = __uint_as_float(((uint32_t)(uint16_t)v1[j]) << 16);
            }
            float* dst = w_out + ((size_t)bh * S_ + row0 + rr) * S_ + t0 + c0;
#pragma unroll
            for (int q = 0; q < 4; ++q)
                *reinterpret_cast<float4*>(dst + q * 4) =
                    make_float4(fs[q*4], fs[q*4+1], fs[q*4+2], fs[q*4+3]);
        }
        // PV accumulation: A from LDS w tile, B from hbT
#pragma unroll
        for (int kk = 0; kk < 2; ++kk) {
            bf16x8 a = *reinterpret_cast<const bf16x8*>(
                &wb[buf][wrow0 + llo][kk * 32 + lhi * 8]);
#pragma unroll
            for (int dt = 0; dt < 4; ++dt) {
                bf16x8 b = *reinterpret_cast<const bf16x8*>(
                    hTbase + (size_t)(dt * 16 + llo) * S_ + t0 + kk * 32 + lhi * 8);
                pv[dt] = mfma16(a, b, pv[dt]);
            }
        }
    }
    // ---- epilogue: store pv bf16 into [B][S][D] layout ----
    const int b_ = bh >> 4, h = bh & (H_ - 1);
#pragma unroll
    for (int dt = 0; dt < 4; ++dt) {
        const int d = dt * 16 + llo;
#pragma unroll
        for (int r = 0; r < 4; ++r) {
            const int s = row0 + wrow0 + lhi * 4 + r;
            pvb[((size_t)(b_ * S_ + s)) * D_ + h * HD_ + d] = f2bf(pv[dt][r]);
        }
    }
}

// ---------------------------------------------------------------------------
// out_proj: out = pv @ W_out + b_out   (M=8192, N=1024, K=1024), fp32 out
// ---------------------------------------------------------------------------
__global__ __launch_bounds__(256) void k_gemm_out(
    const uint16_t* __restrict__ pvb, const uint16_t* __restrict__ WtOut,
    const float* __restrict__ b_out, float* __restrict__ out) {
    const int wave = threadIdx.x >> 6, lane = threadIdx.x & 63;
    const int lhi = lane >> 4, llo = lane & 15;
    const int col0 = blockIdx.x * 64;
    const int row0 = blockIdx.y * 64 + wave * 16;

    const uint16_t* prow = pvb + (size_t)(row0 + llo) * D_;
    f32x4 acc[4] = {};
    for (int kc = 0; kc < D_ / 32; ++kc) {
        const int k0 = kc * 32 + lhi * 8;
        bf16x8 a = *reinterpret_cast<const bf16x8*>(prow + k0);
#pragma unroll
        for (int nt = 0; nt < 4; ++nt) {
            bf16x8 b = *reinterpret_cast<const bf16x8*>(
                WtOut + (size_t)(col0 + nt * 16 + llo) * D_ + k0);
            acc[nt] = mfma16(a, b, acc[nt]);
        }
    }
#pragma unroll
    for (int nt = 0; nt < 4; ++nt) {
        const int c = col0 + nt * 16 + llo;
        const float bias = b_out[c];
#pragma unroll
        for (int r = 0; r < 4; ++r) {
            out[(size_t)(row0 + lhi * 4 + r) * D_ + c] = acc[nt][r] + bias;
        }
    }
}

// ---------------------------------------------------------------------------
extern "C" void kernel_launch(void* const* d_in, const int* in_sizes, int n_in,
                              void* d_out, int out_size, void* d_ws, size_t ws_size,
                              hipStream_t stream) {
    const float* x      = (const float*)d_in[0];
    const float* W_attn = (const float*)d_in[1];
    const float* W_in   = (const float*)d_in[2];
    const float* b_in   = (const float*)d_in[3];
    const float* W_out  = (const float*)d_in[4];
    const float* b_out  = (const float*)d_in[5];

    float* out   = (float*)d_out;                       // [B,S,D]
    float* w_out = out + (size_t)BS_ * D_;              // [B,H,S,S]

    uint8_t* ws = (uint8_t*)d_ws;
    auto carve = [&](size_t elems) {
        uint16_t* p = (uint16_t*)ws;
        ws += ((elems * sizeof(uint16_t) + 255) / 256) * 256;
        return p;
    };
    uint16_t* WtIn  = carve((size_t)D_ * D_);
    uint16_t* WtOut = carve((size_t)D_ * D_);
    uint16_t* WtA   = carve((size_t)H_ * HD_ * HD_);
    uint16_t* xb    = carve((size_t)BS_ * D_);          // aliased below as pvb
    uint16_t* hb    = carve((size_t)BH_ * S_ * HD_);
    uint16_t* hbT   = carve((size_t)BH_ * HD_ * S_);
    uint16_t* qb    = carve((size_t)BH_ * S_ * HD_);
    uint16_t* pvb   = xb;   // live ranges disjoint: xb dead after k_gemm_in

    hipLaunchKernelGGL(k_prep, dim3(2048), dim3(256), 0, stream,
                       W_in, W_out, W_attn, x, WtIn, WtOut, WtA, xb);
    hipLaunchKernelGGL(k_gemm_in, dim3(16, 128), dim3(256), 0, stream,
                       xb, WtIn, b_in, hb);
    hipLaunchKernelGGL(k_transpose, dim3(32, 64), dim3(256), 0, stream, hb, hbT);
    hipLaunchKernelGGL(k_gemm_q, dim3(32, 64), dim3(256), 0, stream, hb, WtA, qb);
    hipLaunchKernelGGL(k_attn_fused, dim3(32, 64), dim3(256), 0, stream,
                       qb, hb, hbT, w_out, pvb);
    hipLaunchKernelGGL(k_gemm_out, dim3(16, 128), dim3(256), 0, stream,
                       pvb, WtOut, b_out, out);
}